// Round 2
// baseline (390.778 us; speedup 1.0000x reference)
//
#include <hip/hip_runtime.h>
#include <stdint.h>

#define N_EDGES 500000
#define N_NODES 100000
#define PREP_NG 4     // node-groups per wave in prep_p
#define TBINS 1280    // dist table bins, step 1/32, range [0,40)

typedef __attribute__((ext_vector_type(8))) short short8;
typedef __attribute__((ext_vector_type(4))) float floatx4;
typedef __attribute__((ext_vector_type(2))) float f32x2;
typedef __attribute__((ext_vector_type(4))) unsigned int u32x4v;
typedef __attribute__((ext_vector_type(2))) int i32x2v;

// RNE (one-time prep only)
__device__ __forceinline__ uint16_t f2bf(float f) {
  union { float f; uint32_t u; } cv; cv.f = f;
  uint32_t u = cv.u;
  return (uint16_t)((u + 0x7FFFu + ((u >> 16) & 1u)) >> 16);
}
// truncating pack of two f32 -> bf16x2 (single v_perm_b32)
__device__ __forceinline__ uint32_t pk2bf(float lo, float hi) {
  return __builtin_amdgcn_perm(__float_as_uint(hi), __float_as_uint(lo), 0x07060302u);
}
__device__ __forceinline__ uint16_t bftrunc(float f) {
  return (uint16_t)(__float_as_uint(f) >> 16);
}
__device__ __forceinline__ float lrelu(float v) { return fmaxf(v, 0.001f * v); }

// unpack bf16x2 word -> f32x2 {lo, hi}; 2 VALU ops, arithmetic on result is v_pk_*
__device__ __forceinline__ f32x2 unpk2(uint32_t u) {
  return (f32x2){ __uint_as_float(u << 16), __uint_as_float(u & 0xFFFF0000u) };
}
// h = lrelu(Pa+Pb + lerp(T0,T1,w)) for one bf16x2 word; pk-fp32 math
__device__ __forceinline__ uint32_t comp2(uint32_t a, uint32_t b, uint32_t t0, uint32_t t1,
                                          f32x2 w2) {
  f32x2 p  = unpk2(a) + unpk2(b);
  f32x2 v0 = unpk2(t0), v1 = unpk2(t1);
  f32x2 r  = p + (v0 + w2 * (v1 - v0));
  f32x2 rl = r * 0.001f;
  return pk2bf(fmaxf(r.x, rl.x), fmaxf(r.y, rl.y));
}
__device__ __forceinline__ floatx4 lrelu4(floatx4 v) {
  floatx4 w = v * 0.001f;
  v.x = fmaxf(v.x, w.x); v.y = fmaxf(v.y, w.y);
  v.z = fmaxf(v.z, w.z); v.w = fmaxf(v.w, w.w);
  return v;
}

// ============ prep0: W1/W2 + W0[0:256] -> MFMA-fragment order (bf16); BE0; pos copy ============
__global__ void prep0_kernel(const float* __restrict__ W0, const float* __restrict__ b0,
                             const float* __restrict__ W1, const float* __restrict__ W2,
                             const float* __restrict__ bemb,
                             uint16_t* __restrict__ w0ab, uint16_t* __restrict__ w1f,
                             uint16_t* __restrict__ w2f, float* __restrict__ be0f,
                             const float* __restrict__ pos, float* __restrict__ out, int npos) {
  int id = blockIdx.x * 256 + threadIdx.x;
  if (id < 32768) {                       // w0ab: ks(4) x ntt(16) x lane(64) x j(8)
    int f = id;
    int j = f & 7, lane = (f >> 3) & 63, ntt = (f >> 9) & 15, ks = f >> 13;
    int k = ks * 32 + (lane >> 4) * 8 + j;
    int row = (ntt < 8) ? k : (128 + k);            // ntt<8 -> P_a cols, else P_b cols
    int col = (ntt & 7) * 16 + (lane & 15);
    w0ab[f] = f2bf(W0[row * 128 + col]);
  } else if (id < 49152) {                // w1f
    int f = id - 32768;
    int j = f & 7, lane = (f >> 3) & 63, nt = (f >> 9) & 7, ks = f >> 12;
    int k = ks * 32 + (lane >> 4) * 8 + j;
    w1f[f] = f2bf(W1[k * 128 + nt * 16 + (lane & 15)]);
  } else if (id < 65536) {                // w2f
    int f = id - 49152;
    int j = f & 7, lane = (f >> 3) & 63, nt = (f >> 9) & 7, ks = f >> 12;
    int k = ks * 32 + (lane >> 4) * 8 + j;
    w2f[f] = f2bf(W2[k * 128 + nt * 16 + (lane & 15)]);
  } else if (id < 66048) {                // BE0[t][n] = bond_emb[t]@W0[256:320] + b0 (f32)
    int t = id - 65536; int ty = t >> 7, n = t & 127;
    float s = b0[n];
    for (int kk = 0; kk < 64; ++kk) s += bemb[ty * 64 + kk] * W0[(256 + kk) * 128 + n];
    be0f[t] = s;
  } else if (id - 66048 < npos) {         // pos -> out
    out[id - 66048] = pos[id - 66048];
  }
}

// ============ prep_tp: merged T-table + P_a/P_b precompute (independent halves) ============
__global__ __attribute__((amdgpu_flat_work_group_size(256, 256)))
void prep_tp_kernel(const float* __restrict__ W0, const float* __restrict__ be0f,
                    uint16_t* __restrict__ T,
                    const float* __restrict__ nemb, const uint16_t* __restrict__ w0ab,
                    uint16_t* __restrict__ Pa, uint16_t* __restrict__ Pb) {
  __shared__ __align__(16) uint16_t aLds[4 * PREP_NG * 16 * 136];
  __shared__ float rbf[64];
  const int tid = threadIdx.x;

  if (blockIdx.x < TBINS) {
    // ---- T-table half: one block per bin ----
    int b = blockIdx.x;
    float dist = (float)b * (1.0f / 32.0f);
    const float delta = 20.0f / 62.0f;
    const float coeff = -0.5f / (delta * delta);
    if (tid < 64) {
      float v;
      if (tid < 63) { float d = dist - (float)tid * delta; v = __expf(coeff * d * d); }
      else v = (dist >= 20.0f) ? 1.0f : 0.0f;
      rbf[tid] = v;
    }
    __syncthreads();
    float sum = 0.0f;
    for (int k = 0; k < 64; ++k) sum += rbf[k];
    float rs = 1.0f / sum;
    for (int o = tid; o < 512; o += 256) {
      int ty = o >> 7, n = o & 127;
      float s = be0f[ty * 128 + n];
      for (int k = 0; k < 64; ++k) s += rbf[k] * rs * W0[(320 + k) * 128 + n];
      T[((size_t)(ty * TBINS + b)) * 128 + n] = f2bf(s);
    }
    return;
  }

  // ---- P half ----
  const int pblk = blockIdx.x - TBINS;
  const int lane = tid & 63;
  const int wave = tid >> 6;
  const int n15 = lane & 15;
  const int quad = lane >> 4;
  uint16_t* myA = aLds + wave * (PREP_NG * 16 * 136);
  const int base = pblk * (64 * PREP_NG) + wave * (16 * PREP_NG);

  {
    const int le = lane >> 2, sub = lane & 3;
#pragma unroll
    for (int it = 0; it < PREP_NG; ++it) {
      int r = base + it * 16 + le; if (r >= N_NODES) r = N_NODES - 1;
      const float4* src = (const float4*)(nemb + (size_t)r * 128);
#pragma unroll
      for (int g = 0; g < 4; ++g) {
        float4 a = src[sub * 8 + g * 2], b = src[sub * 8 + g * 2 + 1];
        uint4 pk;
        pk.x = pk2bf(a.x, a.y); pk.y = pk2bf(a.z, a.w);
        pk.z = pk2bf(b.x, b.y); pk.w = pk2bf(b.z, b.w);
        *(uint4*)(myA + (it * 16 + le) * 136 + sub * 32 + g * 8) = pk;
      }
    }
  }

  const short8* wfv = (const short8*)w0ab + lane;
#pragma unroll
  for (int q = 0; q < 4; ++q) {
    short8 bfr[16];
#pragma unroll
    for (int ks = 0; ks < 4; ++ks)
#pragma unroll
      for (int nq = 0; nq < 4; ++nq)
        bfr[ks * 4 + nq] = wfv[(ks * 16 + q * 4 + nq) * 64];
#pragma unroll
    for (int it = 0; it < PREP_NG; ++it) {
      floatx4 acc[4];
#pragma unroll
      for (int nq = 0; nq < 4; ++nq) acc[nq] = (floatx4){0.f, 0.f, 0.f, 0.f};
#pragma unroll
      for (int ks = 0; ks < 4; ++ks) {
        short8 a = *(const short8*)(myA + (it * 16 + n15) * 136 + ks * 32 + quad * 8);
#pragma unroll
        for (int nq = 0; nq < 4; ++nq)
          acc[nq] = __builtin_amdgcn_mfma_f32_16x16x32_bf16(a, bfr[ks * 4 + nq], acc[nq], 0, 0, 0);
      }
      uint16_t* dst = (q < 2) ? Pa : Pb;
      int cbase = ((q & 1) * 4) * 16 + n15;
#pragma unroll
      for (int nq = 0; nq < 4; ++nq) {
        int c = cbase + nq * 16;
#pragma unroll
        for (int r = 0; r < 4; ++r) {
          int row = base + it * 16 + quad * 4 + r;
          if (row < N_NODES) dst[(size_t)row * 128 + c] = bftrunc(acc[nq][r]);
        }
      }
    }
  }
}

// GEMM for TWO 16-row A-tiles sharing each B-fragment (halves weight VMEM per edge).
__device__ __forceinline__ void gemm_g2(const uint16_t* __restrict__ wf,
                                        const uint16_t* aRow0, const uint16_t* aRow1,
                                        int lane, floatx4* acc0, floatx4* acc1) {
  short8 a0[4], a1[4];
#pragma unroll
  for (int ks = 0; ks < 4; ++ks) {
    a0[ks] = *(const short8*)(aRow0 + ks * 32);
    a1[ks] = *(const short8*)(aRow1 + ks * 32);
  }
  const short8* wv = (const short8*)wf + lane;
#pragma unroll
  for (int ks = 0; ks < 4; ++ks)
#pragma unroll
    for (int nt = 0; nt < 8; ++nt) {
      short8 b = wv[(ks * 8 + nt) * 64];
      acc0[nt] = __builtin_amdgcn_mfma_f32_16x16x32_bf16(a0[ks], b, acc0[nt], 0, 0, 0);
      acc1[nt] = __builtin_amdgcn_mfma_f32_16x16x32_bf16(a1[ks], b, acc1[nt], 0, 0, 0);
    }
}

// epilogue 1: +b1, LN, lrelu -> hA (pk-fp32 vector math)
__device__ __forceinline__ void epilogue1(floatx4* acc, uint16_t* hA, int n15, int quad,
                                          const float* __restrict__ b1,
                                          const float* __restrict__ ln1w,
                                          const float* __restrict__ ln1b) {
  float bv[8], wv[8], bb[8];
#pragma unroll
  for (int nt = 0; nt < 8; ++nt) {
    int col = nt * 16 + n15;
    bv[nt] = b1[col]; wv[nt] = ln1w[col]; bb[nt] = ln1b[col];
  }
  floatx4 s4 = {0.f, 0.f, 0.f, 0.f}, q4 = {0.f, 0.f, 0.f, 0.f};
#pragma unroll
  for (int nt = 0; nt < 8; ++nt) { floatx4 v = acc[nt] + bv[nt]; s4 += v; q4 += v * v; }
#pragma unroll
  for (int m = 1; m <= 8; m <<= 1) {
#pragma unroll
    for (int c = 0; c < 4; ++c) { s4[c] += __shfl_xor(s4[c], m); q4[c] += __shfl_xor(q4[c], m); }
  }
  floatx4 mean = s4 * (1.0f / 128.0f);
  floatx4 var = q4 * (1.0f / 128.0f) - mean * mean;
  floatx4 rstd;
  rstd.x = rsqrtf(var.x + 1e-5f); rstd.y = rsqrtf(var.y + 1e-5f);
  rstd.z = rsqrtf(var.z + 1e-5f); rstd.w = rsqrtf(var.w + 1e-5f);
#pragma unroll
  for (int nt = 0; nt < 8; ++nt) {
    floatx4 v = acc[nt] + bv[nt];
    floatx4 vn = lrelu4((v - mean) * (rstd * wv[nt]) + bb[nt]);
#pragma unroll
    for (int r = 0; r < 4; ++r)
      hA[(quad * 4 + r) * 136 + nt * 16 + n15] = bftrunc(vn[r]);
  }
}

// epilogue 2: +b2, LN, lrelu, force = h@Wo + bo, scatter atomics
__device__ __forceinline__ void epilogue2(floatx4* acc, int n15, int quad, int edge0, int gr0,
                                          const float (*u_lds)[3], const int (*ij_lds)[2],
                                          const float* __restrict__ b2,
                                          const float* __restrict__ ln2w,
                                          const float* __restrict__ ln2b,
                                          const float* __restrict__ Wo,
                                          const float* __restrict__ bo,
                                          float* __restrict__ out) {
  float bv[8], wv[8], bb[8], wo0[8], wo1[8];
#pragma unroll
  for (int nt = 0; nt < 8; ++nt) {
    int col = nt * 16 + n15;
    bv[nt] = b2[col]; wv[nt] = ln2w[col]; bb[nt] = ln2b[col];
    wo0[nt] = Wo[2 * col]; wo1[nt] = Wo[2 * col + 1];
  }
  floatx4 s4 = {0.f, 0.f, 0.f, 0.f}, q4 = {0.f, 0.f, 0.f, 0.f};
#pragma unroll
  for (int nt = 0; nt < 8; ++nt) { floatx4 v = acc[nt] + bv[nt]; s4 += v; q4 += v * v; }
#pragma unroll
  for (int m = 1; m <= 8; m <<= 1) {
#pragma unroll
    for (int c = 0; c < 4; ++c) { s4[c] += __shfl_xor(s4[c], m); q4[c] += __shfl_xor(q4[c], m); }
  }
  floatx4 mean = s4 * (1.0f / 128.0f);
  floatx4 var = q4 * (1.0f / 128.0f) - mean * mean;
  floatx4 rstd;
  rstd.x = rsqrtf(var.x + 1e-5f); rstd.y = rsqrtf(var.y + 1e-5f);
  rstd.z = rsqrtf(var.z + 1e-5f); rstd.w = rsqrtf(var.w + 1e-5f);
  floatx4 f0 = {0.f, 0.f, 0.f, 0.f}, f1 = {0.f, 0.f, 0.f, 0.f};
#pragma unroll
  for (int nt = 0; nt < 8; ++nt) {
    floatx4 v = acc[nt] + bv[nt];
    floatx4 vn = lrelu4((v - mean) * (rstd * wv[nt]) + bb[nt]);
    f0 += vn * wo0[nt];
    f1 += vn * wo1[nt];
  }
#pragma unroll
  for (int m = 1; m <= 8; m <<= 1) {
#pragma unroll
    for (int c = 0; c < 4; ++c) { f0[c] += __shfl_xor(f0[c], m); f1[c] += __shfl_xor(f1[c], m); }
  }
  if (n15 < 4) {
    int gr = gr0 + quad * 4 + n15;
    int ge2 = edge0 + quad * 4 + n15;
    if (ge2 < N_EDGES) {
      float F0 = (n15 == 0) ? f0.x : (n15 == 1) ? f0.y : (n15 == 2) ? f0.z : f0.w;
      float F1 = (n15 == 0) ? f1.x : (n15 == 1) ? f1.y : (n15 == 2) ? f1.z : f1.w;
      F0 += bo[0]; F1 += bo[1];
      float ux = u_lds[gr][0], uy = u_lds[gr][1], uz = u_lds[gr][2];
      int ii = ij_lds[gr][0], jj = ij_lds[gr][1];
      float c0 = 0.5f * F0;          // STEP * force0, along +u
      float c1 = -0.5f * F1;         // STEP * force1, along -u
      atomicAdd(out + 3 * ii,     c0 * ux);
      atomicAdd(out + 3 * ii + 1, c0 * uy);
      atomicAdd(out + 3 * ii + 2, c0 * uz);
      atomicAdd(out + 3 * jj,     c1 * ux);
      atomicAdd(out + 3 * jj + 1, c1 * uy);
      atomicAdd(out + 3 * jj + 2, c1 * uz);
    }
  }
}

// ============ main: 128 edges/block, 4 waves, 32 edges/wave (2 MFMA tiles) ============
// All LDS wave-private -> zero barriers. B-fragments from global (L1/L2-resident),
// each fragment feeds 2 MFMAs (weight line-traffic per edge halved vs 16-edge waves).
// Gathers (Pa/Pb/bidx/btyp) nontemporal so weights stay L1-resident.
__global__ __attribute__((amdgpu_flat_work_group_size(256, 256), amdgpu_waves_per_eu(2, 4)))
void bond_mlp_kernel(const float* __restrict__ x,
                     const int* __restrict__ bidx, const int* __restrict__ btyp,
                     const uint16_t* __restrict__ Pa, const uint16_t* __restrict__ Pb,
                     const uint16_t* __restrict__ Tt, const uint16_t* __restrict__ w1f,
                     const uint16_t* __restrict__ w2f,
                     const float* __restrict__ b1, const float* __restrict__ ln1w,
                     const float* __restrict__ ln1b,
                     const float* __restrict__ b2, const float* __restrict__ ln2w,
                     const float* __restrict__ ln2b,
                     const float* __restrict__ Wo, const float* __restrict__ bo,
                     float* __restrict__ out) {
  __shared__ __align__(16) uint16_t hA_all[8 * 16 * 136];   // 4 waves x 2 groups
  __shared__ float u_lds[128][3];
  __shared__ int ij_lds[128][2];

  const int tid = threadIdx.x;
  const int lane = tid & 63;
  const int wave = tid >> 6;
  const int n15 = lane & 15;
  const int quad = lane >> 4;

  uint16_t* hA0 = hA_all + (wave * 2 + 0) * (16 * 136);
  uint16_t* hA1 = hA_all + (wave * 2 + 1) * (16 * 136);

  // ---- phase 1: h0 = lrelu(Pa[i]+Pb[j]+lerp(T[t],dist)) for both groups ----
#pragma unroll
  for (int g = 0; g < 2; ++g) {
    uint16_t* hA = (g == 0) ? hA0 : hA1;
    const int le = lane >> 2, sub = lane & 3;   // 4 lanes per edge
    const int gr = wave * 32 + g * 16 + le;
    const int ge = blockIdx.x * 128 + gr;
    const bool valid = ge < N_EDGES;
    int vi = 0, vj = 0, bt = 0;
    if (valid) {
      i32x2v ij = __builtin_nontemporal_load((const i32x2v*)(bidx + 2 * ge));
      vi = ij.x; vj = ij.y;
      bt = __builtin_nontemporal_load(btyp + ge);
    }
    float dx, dy, dz;
    if (valid) {
      dx = x[3 * vi]     - x[3 * vj];
      dy = x[3 * vi + 1] - x[3 * vj + 1];
      dz = x[3 * vi + 2] - x[3 * vj + 2];
    } else { dx = 1.0f; dy = 0.0f; dz = 0.0f; }
    float dist = sqrtf(dx * dx + dy * dy + dz * dz);
    float rinv = 1.0f / dist;
    if (sub == 0) {
      u_lds[gr][0] = dx * rinv; u_lds[gr][1] = dy * rinv; u_lds[gr][2] = dz * rinv;
      ij_lds[gr][0] = vi; ij_lds[gr][1] = vj;
    }
    float fb = fminf(dist, 39.5f) * 32.0f;
    int bi = (int)fb;
    float w = fb - (float)bi;
    f32x2 w2 = {w, w};
    const u32x4v* pa = (const u32x4v*)(Pa + (size_t)vi * 128 + sub * 32);
    const u32x4v* pb = (const u32x4v*)(Pb + (size_t)vj * 128 + sub * 32);
    const uint16_t* trow = Tt + ((size_t)(bt * TBINS + bi)) * 128 + sub * 32;
    const u32x4v* t0p = (const u32x4v*)trow;
    const u32x4v* t1p = (const u32x4v*)(trow + 128);
#pragma unroll
    for (int gg = 0; gg < 4; ++gg) {
      u32x4v av = __builtin_nontemporal_load(pa + gg);
      u32x4v bw = __builtin_nontemporal_load(pb + gg);
      u32x4v t0 = t0p[gg];
      u32x4v t1 = t1p[gg];
      u32x4v pk;
      pk.x = comp2(av.x, bw.x, t0.x, t1.x, w2);
      pk.y = comp2(av.y, bw.y, t0.y, t1.y, w2);
      pk.z = comp2(av.z, bw.z, t0.z, t1.z, w2);
      pk.w = comp2(av.w, bw.w, t0.w, t1.w, w2);
      *(u32x4v*)(hA + le * 136 + sub * 32 + gg * 8) = pk;
    }
  }
  // no barrier: hA/u_lds/ij_lds are wave-private; compiler inserts lgkmcnt waits

  const uint16_t* aRow0 = hA0 + n15 * 136 + quad * 8;
  const uint16_t* aRow1 = hA1 + n15 * 136 + quad * 8;

  floatx4 acc0[8], acc1[8];
#pragma unroll
  for (int nt = 0; nt < 8; ++nt) {
    acc0[nt] = (floatx4){0.f, 0.f, 0.f, 0.f};
    acc1[nt] = (floatx4){0.f, 0.f, 0.f, 0.f};
  }
  gemm_g2(w1f, aRow0, aRow1, lane, acc0, acc1);   // L1 for both groups

  epilogue1(acc0, hA0, n15, quad, b1, ln1w, ln1b);
  epilogue1(acc1, hA1, n15, quad, b1, ln1w, ln1b);
  // no barrier: hA is wave-private

#pragma unroll
  for (int nt = 0; nt < 8; ++nt) {
    acc0[nt] = (floatx4){0.f, 0.f, 0.f, 0.f};
    acc1[nt] = (floatx4){0.f, 0.f, 0.f, 0.f};
  }
  gemm_g2(w2f, aRow0, aRow1, lane, acc0, acc1);   // L2 for both groups

  const int e0 = blockIdx.x * 128 + wave * 32;
  epilogue2(acc0, n15, quad, e0,      wave * 32,      u_lds, ij_lds, b2, ln2w, ln2b, Wo, bo, out);
  epilogue2(acc1, n15, quad, e0 + 16, wave * 32 + 16, u_lds, ij_lds, b2, ln2w, ln2b, Wo, bo, out);
}

extern "C" void kernel_launch(void* const* d_in, const int* in_sizes, int n_in,
                              void* d_out, int out_size, void* d_ws, size_t ws_size,
                              hipStream_t stream) {
  const float* x    = (const float*)d_in[0];
  const float* pos  = (const float*)d_in[1];
  const float* nemb = (const float*)d_in[2];
  const int*   bidx = (const int*)d_in[3];
  const int*   btyp = (const int*)d_in[4];
  const float* bemb = (const float*)d_in[5];
  const float* W0   = (const float*)d_in[6];
  const float* b0   = (const float*)d_in[7];
  const float* W1   = (const float*)d_in[8];
  const float* b1   = (const float*)d_in[9];
  const float* ln1w = (const float*)d_in[10];
  const float* ln1b = (const float*)d_in[11];
  const float* W2   = (const float*)d_in[12];
  const float* b2   = (const float*)d_in[13];
  const float* ln2w = (const float*)d_in[14];
  const float* ln2b = (const float*)d_in[15];
  const float* Wo   = (const float*)d_in[16];
  const float* bo   = (const float*)d_in[17];
  float* out = (float*)d_out;

  // ws: frag weights 128KB + be0 2KB + T 1.31MB + Pa/Pb 51.2MB
  uint16_t* w0ab = (uint16_t*)d_ws;                 // 32768 bf16
  uint16_t* w1f  = w0ab + 32768;                    // 16384
  uint16_t* w2f  = w1f + 16384;                     // 16384
  float*    be0f = (float*)(w2f + 16384);           // 512 f32
  uint16_t* Tt   = (uint16_t*)(be0f + 512);         // 4*TBINS*128 bf16
  uint16_t* Pa   = Tt + (size_t)4 * TBINS * 128;    // N_NODES*128 bf16
  uint16_t* Pb   = Pa + (size_t)N_NODES * 128;      // N_NODES*128 bf16

  const int nblkP = (N_NODES + 64 * PREP_NG - 1) / (64 * PREP_NG);

  prep0_kernel<<<(66048 + out_size + 255) / 256, 256, 0, stream>>>(
      W0, b0, W1, W2, bemb, w0ab, w1f, w2f, be0f, pos, out, out_size);
  prep_tp_kernel<<<TBINS + nblkP, 256, 0, stream>>>(
      W0, be0f, Tt, nemb, w0ab, Pa, Pb);
  bond_mlp_kernel<<<(N_EDGES + 127) / 128, 256, 0, stream>>>(
      x, bidx, btyp, Pa, Pb, Tt, w1f, w2f,
      b1, ln1w, ln1b, b2, ln2w, ln2b, Wo, bo, out);
}

// Round 3
// 352.555 us; speedup vs baseline: 1.1084x; 1.1084x over previous
//
#include <hip/hip_runtime.h>
#include <stdint.h>

#define N_EDGES 500000
#define N_NODES 100000
#define PREP_NG 2     // node-groups per wave in prep_p
#define TBINS 5120    // dist table bins, step 1/128, range [0,40); nearest-bin lookup

typedef __attribute__((ext_vector_type(8))) short short8;
typedef __attribute__((ext_vector_type(4))) float floatx4;
typedef __attribute__((ext_vector_type(2))) float f32x2;

// RNE (one-time prep only)
__device__ __forceinline__ uint16_t f2bf(float f) {
  union { float f; uint32_t u; } cv; cv.f = f;
  uint32_t u = cv.u;
  return (uint16_t)((u + 0x7FFFu + ((u >> 16) & 1u)) >> 16);
}
// truncating pack of two f32 -> bf16x2 (single v_perm_b32)
__device__ __forceinline__ uint32_t pk2bf(float lo, float hi) {
  return __builtin_amdgcn_perm(__float_as_uint(hi), __float_as_uint(lo), 0x07060302u);
}
__device__ __forceinline__ uint16_t bftrunc(float f) {
  return (uint16_t)(__float_as_uint(f) >> 16);
}
__device__ __forceinline__ float lrelu(float v) { return fmaxf(v, 0.001f * v); }

// unpack bf16x2 word -> f32x2 {lo, hi}
__device__ __forceinline__ f32x2 unpk2(uint32_t u) {
  return (f32x2){ __uint_as_float(u << 16), __uint_as_float(u & 0xFFFF0000u) };
}
// h = lrelu(Pa+Pb+T) for one bf16x2 word (nearest-bin T: no lerp)
__device__ __forceinline__ uint32_t comp2n(uint32_t a, uint32_t b, uint32_t t) {
  f32x2 r = unpk2(a) + unpk2(b) + unpk2(t);
  f32x2 rl = r * 0.001f;
  return pk2bf(fmaxf(r.x, rl.x), fmaxf(r.y, rl.y));
}
__device__ __forceinline__ floatx4 lrelu4(floatx4 v) {
  floatx4 w = v * 0.001f;
  v.x = fmaxf(v.x, w.x); v.y = fmaxf(v.y, w.y);
  v.z = fmaxf(v.z, w.z); v.w = fmaxf(v.w, w.w);
  return v;
}

// ============ prep0: W1/W2 + W0[0:256] -> MFMA-fragment order (bf16); BE0; pos copy ============
__global__ void prep0_kernel(const float* __restrict__ W0, const float* __restrict__ b0,
                             const float* __restrict__ W1, const float* __restrict__ W2,
                             const float* __restrict__ bemb,
                             uint16_t* __restrict__ w0ab, uint16_t* __restrict__ w1f,
                             uint16_t* __restrict__ w2f, float* __restrict__ be0f,
                             const float* __restrict__ pos, float* __restrict__ out, int npos) {
  int id = blockIdx.x * 256 + threadIdx.x;
  if (id < 32768) {                       // w0ab: ks(4) x ntt(16) x lane(64) x j(8)
    int f = id;
    int j = f & 7, lane = (f >> 3) & 63, ntt = (f >> 9) & 15, ks = f >> 13;
    int k = ks * 32 + (lane >> 4) * 8 + j;
    int row = (ntt < 8) ? k : (128 + k);            // ntt<8 -> P_a cols, else P_b cols
    int col = (ntt & 7) * 16 + (lane & 15);
    w0ab[f] = f2bf(W0[row * 128 + col]);
  } else if (id < 49152) {                // w1f
    int f = id - 32768;
    int j = f & 7, lane = (f >> 3) & 63, nt = (f >> 9) & 7, ks = f >> 12;
    int k = ks * 32 + (lane >> 4) * 8 + j;
    w1f[f] = f2bf(W1[k * 128 + nt * 16 + (lane & 15)]);
  } else if (id < 65536) {                // w2f
    int f = id - 49152;
    int j = f & 7, lane = (f >> 3) & 63, nt = (f >> 9) & 7, ks = f >> 12;
    int k = ks * 32 + (lane >> 4) * 8 + j;
    w2f[f] = f2bf(W2[k * 128 + nt * 16 + (lane & 15)]);
  } else if (id < 66048) {                // BE0[t][n] = bond_emb[t]@W0[256:320] + b0 (f32)
    int t = id - 65536; int ty = t >> 7, n = t & 127;
    float s = b0[n];
    for (int kk = 0; kk < 64; ++kk) s += bemb[ty * 64 + kk] * W0[(256 + kk) * 128 + n];
    be0f[t] = s;
  } else if (id - 66048 < npos) {         // pos -> out
    out[id - 66048] = pos[id - 66048];
  }
}

// ============ prep_tp: merged T-table + P_a/P_b precompute (independent halves) ============
// blocks [0, TBINS):       T[t][b][n] = smear(dist_b)@W0[320:384] + BE0[t][n] (bf16)
// blocks [TBINS, +nblkP):  P_a = nemb @ W0[0:128], P_b = nemb @ W0[128:256] (bf16)
// P-half stores go through a per-wave LDS transpose so globals are dwordx4
// (was 128 scalar 2-B stores per wave per (q,it) -- the prep bottleneck).
__global__ __attribute__((amdgpu_flat_work_group_size(256, 256)))
void prep_tp_kernel(const float* __restrict__ W0, const float* __restrict__ be0f,
                    uint16_t* __restrict__ T,
                    const float* __restrict__ nemb, const uint16_t* __restrict__ w0ab,
                    uint16_t* __restrict__ Pa, uint16_t* __restrict__ Pb) {
  __shared__ __align__(16) uint16_t aLds[4 * PREP_NG * 16 * 136];
  __shared__ __align__(16) uint16_t sS[4][16][72];   // per-wave store staging (72 = 64+8 pad)
  __shared__ float rbf[64];
  const int tid = threadIdx.x;

  if (blockIdx.x < TBINS) {
    // ---- T-table half: one block per bin ----
    int b = blockIdx.x;
    float dist = (float)b * (1.0f / 128.0f);
    const float delta = 20.0f / 62.0f;
    const float coeff = -0.5f / (delta * delta);
    if (tid < 64) {
      float v;
      if (tid < 63) { float d = dist - (float)tid * delta; v = __expf(coeff * d * d); }
      else v = (dist >= 20.0f) ? 1.0f : 0.0f;
      rbf[tid] = v;
    }
    __syncthreads();
    float sum = 0.0f;
    for (int k = 0; k < 64; ++k) sum += rbf[k];
    float rs = 1.0f / sum;
    for (int o = tid; o < 512; o += 256) {
      int ty = o >> 7, n = o & 127;
      float s = be0f[ty * 128 + n];
      for (int k = 0; k < 64; ++k) s += rbf[k] * rs * W0[(320 + k) * 128 + n];
      T[((size_t)(ty * TBINS + b)) * 128 + n] = f2bf(s);
    }
    return;
  }

  // ---- P half ----
  const int pblk = blockIdx.x - TBINS;
  const int lane = tid & 63;
  const int wave = tid >> 6;
  const int n15 = lane & 15;
  const int quad = lane >> 4;
  uint16_t* myA = aLds + wave * (PREP_NG * 16 * 136);
  const int base = pblk * (64 * PREP_NG) + wave * (16 * PREP_NG);

  {
    const int le = lane >> 2, sub = lane & 3;
#pragma unroll
    for (int it = 0; it < PREP_NG; ++it) {
      int r = base + it * 16 + le; if (r >= N_NODES) r = N_NODES - 1;
      const float4* src = (const float4*)(nemb + (size_t)r * 128);
#pragma unroll
      for (int g = 0; g < 4; ++g) {
        float4 a = src[sub * 8 + g * 2], b = src[sub * 8 + g * 2 + 1];
        uint4 pk;
        pk.x = pk2bf(a.x, a.y); pk.y = pk2bf(a.z, a.w);
        pk.z = pk2bf(b.x, b.y); pk.w = pk2bf(b.z, b.w);
        *(uint4*)(myA + (it * 16 + le) * 136 + sub * 32 + g * 8) = pk;
      }
    }
  }

  const short8* wfv = (const short8*)w0ab + lane;
  const int srow = lane >> 2, sch = lane & 3;   // store read-back mapping
#pragma unroll
  for (int q = 0; q < 4; ++q) {
    short8 bfr[16];
#pragma unroll
    for (int ks = 0; ks < 4; ++ks)
#pragma unroll
      for (int nq = 0; nq < 4; ++nq)
        bfr[ks * 4 + nq] = wfv[(ks * 16 + q * 4 + nq) * 64];
    uint16_t* dst = (q < 2) ? Pa : Pb;
    const int cbase = (q & 1) * 64;
#pragma unroll
    for (int it = 0; it < PREP_NG; ++it) {
      floatx4 acc[4];
#pragma unroll
      for (int nq = 0; nq < 4; ++nq) acc[nq] = (floatx4){0.f, 0.f, 0.f, 0.f};
#pragma unroll
      for (int ks = 0; ks < 4; ++ks) {
        short8 a = *(const short8*)(myA + (it * 16 + n15) * 136 + ks * 32 + quad * 8);
#pragma unroll
        for (int nq = 0; nq < 4; ++nq)
          acc[nq] = __builtin_amdgcn_mfma_f32_16x16x32_bf16(a, bfr[ks * 4 + nq], acc[nq], 0, 0, 0);
      }
      // stage MFMA-layout acc into LDS, read back row-major, store dwordx4
#pragma unroll
      for (int nq = 0; nq < 4; ++nq)
#pragma unroll
        for (int r = 0; r < 4; ++r)
          sS[wave][quad * 4 + r][nq * 16 + n15] = bftrunc(acc[nq][r]);
      int grow = base + it * 16 + srow;
      if (grow < N_NODES) {
        uint16_t* drow = dst + (size_t)grow * 128 + cbase;
#pragma unroll
        for (int h = 0; h < 2; ++h)
          *(uint4*)(drow + (h * 4 + sch) * 8) =
              *(const uint4*)&sS[wave][srow][(h * 4 + sch) * 8];
      }
    }
  }
}

// GEMM with B-fragments read straight from global (w1f/w2f are 32KB each and
// read by every block -> permanently L1/L2-resident).
__device__ __forceinline__ void gemm_g(const uint16_t* __restrict__ wf, const uint16_t* aRow,
                                       int lane, floatx4* acc) {
  short8 a[4];
#pragma unroll
  for (int ks = 0; ks < 4; ++ks) a[ks] = *(const short8*)(aRow + ks * 32);
  const short8* wv = (const short8*)wf + lane;
#pragma unroll
  for (int ks = 0; ks < 4; ++ks)
#pragma unroll
    for (int nt = 0; nt < 8; ++nt)
      acc[nt] = __builtin_amdgcn_mfma_f32_16x16x32_bf16(a[ks], wv[(ks * 8 + nt) * 64], acc[nt], 0, 0, 0);
}

// ============ main: 64 edges/block, 4 waves, 16 edges/wave (R1 structure) ============
// All LDS wave-private -> zero barriers. Nearest-bin T (one row, not two).
__global__ __attribute__((amdgpu_flat_work_group_size(256, 256), amdgpu_waves_per_eu(4)))
void bond_mlp_kernel(const float* __restrict__ x,
                     const int* __restrict__ bidx, const int* __restrict__ btyp,
                     const uint16_t* __restrict__ Pa, const uint16_t* __restrict__ Pb,
                     const uint16_t* __restrict__ Tt, const uint16_t* __restrict__ w1f,
                     const uint16_t* __restrict__ w2f,
                     const float* __restrict__ b1, const float* __restrict__ ln1w,
                     const float* __restrict__ ln1b,
                     const float* __restrict__ b2, const float* __restrict__ ln2w,
                     const float* __restrict__ ln2b,
                     const float* __restrict__ Wo, const float* __restrict__ bo,
                     float* __restrict__ out) {
  __shared__ __align__(16) uint16_t hA_all[4 * 16 * 136];   // wave-private slices
  __shared__ float u_lds[64][3];
  __shared__ int ij_lds[64][2];

  const int tid = threadIdx.x;
  const int lane = tid & 63;
  const int wave = tid >> 6;
  const int n15 = lane & 15;
  const int quad = lane >> 4;

  uint16_t* hA = hA_all + wave * (16 * 136);

  // ---- phase 1: h0 = lrelu(Pa[i]+Pb[j]+T[t][bin(dist)]) -> hA (A-layout, bf16) ----
  {
    const int le = lane >> 2, sub = lane & 3;   // 4 lanes per edge
    const int gr = wave * 16 + le;
    const int ge = blockIdx.x * 64 + gr;
    const bool valid = ge < N_EDGES;
    int vi = 0, vj = 0, bt = 0;
    if (valid) {
      int2 ij = *(const int2*)(bidx + 2 * ge);
      vi = ij.x; vj = ij.y;
      bt = btyp[ge];
    }
    float dx, dy, dz;
    if (valid) {
      dx = x[3 * vi]     - x[3 * vj];
      dy = x[3 * vi + 1] - x[3 * vj + 1];
      dz = x[3 * vi + 2] - x[3 * vj + 2];
    } else { dx = 1.0f; dy = 0.0f; dz = 0.0f; }
    float dist = sqrtf(dx * dx + dy * dy + dz * dz);
    float rinv = 1.0f / dist;
    if (sub == 0) {
      u_lds[gr][0] = dx * rinv; u_lds[gr][1] = dy * rinv; u_lds[gr][2] = dz * rinv;
      ij_lds[gr][0] = vi; ij_lds[gr][1] = vj;
    }
    // nearest bin, step 1/128
    int bi = (int)(fminf(dist, 39.9f) * 128.0f + 0.5f);
    const uint4* pa = (const uint4*)(Pa + (size_t)vi * 128 + sub * 32);
    const uint4* pb = (const uint4*)(Pb + (size_t)vj * 128 + sub * 32);
    const uint4* tp = (const uint4*)(Tt + ((size_t)(bt * TBINS + bi)) * 128 + sub * 32);
#pragma unroll
    for (int g = 0; g < 4; ++g) {
      uint4 av = pa[g], bv = pb[g], tv = tp[g];
      uint4 pk;
      pk.x = comp2n(av.x, bv.x, tv.x);
      pk.y = comp2n(av.y, bv.y, tv.y);
      pk.z = comp2n(av.z, bv.z, tv.z);
      pk.w = comp2n(av.w, bv.w, tv.w);
      *(uint4*)(hA + le * 136 + sub * 32 + g * 8) = pk;
    }
  }
  // no barrier: hA/u_lds/ij_lds are wave-private; compiler inserts lgkmcnt waits

  const uint16_t* aRow = hA + n15 * 136 + quad * 8;

  floatx4 acc[8];
#pragma unroll
  for (int nt = 0; nt < 8; ++nt) acc[nt] = (floatx4){0.f, 0.f, 0.f, 0.f};
  gemm_g(w1f, aRow, lane, acc);          // L1, B from global (L2-resident)

  // epilogue 1: +b1, LN, lrelu -> hA
  {
    float bv[8], wv[8], bb[8];
#pragma unroll
    for (int nt = 0; nt < 8; ++nt) {
      int col = nt * 16 + n15;
      bv[nt] = b1[col]; wv[nt] = ln1w[col]; bb[nt] = ln1b[col];
    }
    floatx4 s4 = {0.f, 0.f, 0.f, 0.f}, q4 = {0.f, 0.f, 0.f, 0.f};
#pragma unroll
    for (int nt = 0; nt < 8; ++nt) { floatx4 v = acc[nt] + bv[nt]; s4 += v; q4 += v * v; }
#pragma unroll
    for (int m = 1; m <= 8; m <<= 1) {
#pragma unroll
      for (int c = 0; c < 4; ++c) { s4[c] += __shfl_xor(s4[c], m); q4[c] += __shfl_xor(q4[c], m); }
    }
    floatx4 mean = s4 * (1.0f / 128.0f);
    floatx4 var = q4 * (1.0f / 128.0f) - mean * mean;
    floatx4 rstd;
    rstd.x = rsqrtf(var.x + 1e-5f); rstd.y = rsqrtf(var.y + 1e-5f);
    rstd.z = rsqrtf(var.z + 1e-5f); rstd.w = rsqrtf(var.w + 1e-5f);
#pragma unroll
    for (int nt = 0; nt < 8; ++nt) {
      floatx4 v = acc[nt] + bv[nt];
      floatx4 vn = lrelu4((v - mean) * (rstd * wv[nt]) + bb[nt]);
#pragma unroll
      for (int r = 0; r < 4; ++r)
        hA[(quad * 4 + r) * 136 + nt * 16 + n15] = bftrunc(vn[r]);
    }
  }
  // no barrier: hA is wave-private

#pragma unroll
  for (int nt = 0; nt < 8; ++nt) acc[nt] = (floatx4){0.f, 0.f, 0.f, 0.f};
  gemm_g(w2f, aRow, lane, acc);          // L2, B from global (L2-resident)

  // epilogue 2: +b2, LN, lrelu, force = h@Wo + bo, scatter atomics
  {
    float bv[8], wv[8], bb[8], wo0[8], wo1[8];
#pragma unroll
    for (int nt = 0; nt < 8; ++nt) {
      int col = nt * 16 + n15;
      bv[nt] = b2[col]; wv[nt] = ln2w[col]; bb[nt] = ln2b[col];
      wo0[nt] = Wo[2 * col]; wo1[nt] = Wo[2 * col + 1];
    }
    floatx4 s4 = {0.f, 0.f, 0.f, 0.f}, q4 = {0.f, 0.f, 0.f, 0.f};
#pragma unroll
    for (int nt = 0; nt < 8; ++nt) { floatx4 v = acc[nt] + bv[nt]; s4 += v; q4 += v * v; }
#pragma unroll
    for (int m = 1; m <= 8; m <<= 1) {
#pragma unroll
      for (int c = 0; c < 4; ++c) { s4[c] += __shfl_xor(s4[c], m); q4[c] += __shfl_xor(q4[c], m); }
    }
    floatx4 mean = s4 * (1.0f / 128.0f);
    floatx4 var = q4 * (1.0f / 128.0f) - mean * mean;
    floatx4 rstd;
    rstd.x = rsqrtf(var.x + 1e-5f); rstd.y = rsqrtf(var.y + 1e-5f);
    rstd.z = rsqrtf(var.z + 1e-5f); rstd.w = rsqrtf(var.w + 1e-5f);
    floatx4 f0 = {0.f, 0.f, 0.f, 0.f}, f1 = {0.f, 0.f, 0.f, 0.f};
#pragma unroll
    for (int nt = 0; nt < 8; ++nt) {
      floatx4 v = acc[nt] + bv[nt];
      floatx4 vn = lrelu4((v - mean) * (rstd * wv[nt]) + bb[nt]);
      f0 += vn * wo0[nt];
      f1 += vn * wo1[nt];
    }
#pragma unroll
    for (int m = 1; m <= 8; m <<= 1) {
#pragma unroll
      for (int c = 0; c < 4; ++c) { f0[c] += __shfl_xor(f0[c], m); f1[c] += __shfl_xor(f1[c], m); }
    }
    if (n15 < 4) {
      int gr = wave * 16 + quad * 4 + n15;
      int ge2 = blockIdx.x * 64 + gr;
      if (ge2 < N_EDGES) {
        float F0 = (n15 == 0) ? f0.x : (n15 == 1) ? f0.y : (n15 == 2) ? f0.z : f0.w;
        float F1 = (n15 == 0) ? f1.x : (n15 == 1) ? f1.y : (n15 == 2) ? f1.z : f1.w;
        F0 += bo[0]; F1 += bo[1];
        float ux = u_lds[gr][0], uy = u_lds[gr][1], uz = u_lds[gr][2];
        int ii = ij_lds[gr][0], jj = ij_lds[gr][1];
        float c0 = 0.5f * F0;          // STEP * force0, along +u
        float c1 = -0.5f * F1;         // STEP * force1, along -u
        atomicAdd(out + 3 * ii,     c0 * ux);
        atomicAdd(out + 3 * ii + 1, c0 * uy);
        atomicAdd(out + 3 * ii + 2, c0 * uz);
        atomicAdd(out + 3 * jj,     c1 * ux);
        atomicAdd(out + 3 * jj + 1, c1 * uy);
        atomicAdd(out + 3 * jj + 2, c1 * uz);
      }
    }
  }
}

extern "C" void kernel_launch(void* const* d_in, const int* in_sizes, int n_in,
                              void* d_out, int out_size, void* d_ws, size_t ws_size,
                              hipStream_t stream) {
  const float* x    = (const float*)d_in[0];
  const float* pos  = (const float*)d_in[1];
  const float* nemb = (const float*)d_in[2];
  const int*   bidx = (const int*)d_in[3];
  const int*   btyp = (const int*)d_in[4];
  const float* bemb = (const float*)d_in[5];
  const float* W0   = (const float*)d_in[6];
  const float* b0   = (const float*)d_in[7];
  const float* W1   = (const float*)d_in[8];
  const float* b1   = (const float*)d_in[9];
  const float* ln1w = (const float*)d_in[10];
  const float* ln1b = (const float*)d_in[11];
  const float* W2   = (const float*)d_in[12];
  const float* b2   = (const float*)d_in[13];
  const float* ln2w = (const float*)d_in[14];
  const float* ln2b = (const float*)d_in[15];
  const float* Wo   = (const float*)d_in[16];
  const float* bo   = (const float*)d_in[17];
  float* out = (float*)d_out;

  // ws: frag weights 128KB + be0 2KB + T 5.24MB + Pa/Pb 51.2MB
  uint16_t* w0ab = (uint16_t*)d_ws;                 // 32768 bf16
  uint16_t* w1f  = w0ab + 32768;                    // 16384
  uint16_t* w2f  = w1f + 16384;                     // 16384
  float*    be0f = (float*)(w2f + 16384);           // 512 f32
  uint16_t* Tt   = (uint16_t*)(be0f + 512);         // 4*TBINS*128 bf16
  uint16_t* Pa   = Tt + (size_t)4 * TBINS * 128;    // N_NODES*128 bf16
  uint16_t* Pb   = Pa + (size_t)N_NODES * 128;      // N_NODES*128 bf16

  const int nblkP = (N_NODES + 64 * PREP_NG - 1) / (64 * PREP_NG);

  prep0_kernel<<<(66048 + out_size + 255) / 256, 256, 0, stream>>>(
      W0, b0, W1, W2, bemb, w0ab, w1f, w2f, be0f, pos, out, out_size);
  prep_tp_kernel<<<TBINS + nblkP, 256, 0, stream>>>(
      W0, be0f, Tt, nemb, w0ab, Pa, Pb);
  bond_mlp_kernel<<<(N_EDGES + 63) / 64, 256, 0, stream>>>(
      x, bidx, btyp, Pa, Pb, Tt, w1f, w2f,
      b1, ln1w, ln1b, b2, ln2w, ln2b, Wo, bo, out);
}